// Round 1
// baseline (702.814 us; speedup 1.0000x reference)
//
#include <hip/hip_runtime.h>

// Problem constants (from reference setup_inputs): N=4, H=W=512, C_IN=4, C_OUT=31.
// out[n,o,hw] = r*C[n,o,hw] + g*C[n,31+o,hw] + b*C[n,62+o,hw] + 1*C[n,93+o,hw]
// Purely HBM-bound: ~663 MB total traffic -> ~105 us floor at 6.3 TB/s.

#define C_OUT 31

__global__ __launch_bounds__(256)
void ApplyCoeffs_23261542875222_kernel(const float4* __restrict__ coeff,
                                       const float4* __restrict__ inp,
                                       float4* __restrict__ out,
                                       int p4)  // HW/4 = pixels-per-image / 4
{
    int t = blockIdx.x * blockDim.x + threadIdx.x;
    int n = t / p4;           // image index
    int p = t - n * p4;       // float4-pixel index within image

    // Input: [N, 3, HW] -- load r,g,b once, hold in registers across all 31 o.
    const float4* in_n = inp + (size_t)n * 3 * p4;
    float4 r = in_n[p];
    float4 g = in_n[p + p4];
    float4 b = in_n[p + 2 * p4];

    // Coeff: [N, 4*C_OUT, HW]; channel c = i*C_OUT + o.
    const float4* co = coeff + (size_t)n * 4 * C_OUT * p4 + p;
    float4* on = out + (size_t)n * C_OUT * p4 + p;

    #pragma unroll 4
    for (int o = 0; o < C_OUT; ++o) {
        float4 c0 = co[(size_t)o * p4];
        float4 c1 = co[(size_t)(C_OUT + o) * p4];
        float4 c2 = co[(size_t)(2 * C_OUT + o) * p4];
        float4 c3 = co[(size_t)(3 * C_OUT + o) * p4];
        float4 v;
        v.x = r.x * c0.x + g.x * c1.x + b.x * c2.x + c3.x;
        v.y = r.y * c0.y + g.y * c1.y + b.y * c2.y + c3.y;
        v.z = r.z * c0.z + g.z * c1.z + b.z * c2.z + c3.z;
        v.w = r.w * c0.w + g.w * c1.w + b.w * c2.w + c3.w;
        on[(size_t)o * p4] = v;
    }
}

extern "C" void kernel_launch(void* const* d_in, const int* in_sizes, int n_in,
                              void* d_out, int out_size, void* d_ws, size_t ws_size,
                              hipStream_t stream) {
    const float* coeff = (const float*)d_in[0];          // [4, 124, 512, 512]
    const float* inp   = (const float*)d_in[1];          // [4, 3, 512, 512]
    float* out         = (float*)d_out;                  // [4, 31, 512, 512]

    const int N = 4;
    const int HW = 512 * 512;
    const int P4 = HW / 4;              // 65536 float4-pixels per image
    const int total = N * P4;           // 262144 threads
    dim3 block(256);
    dim3 grid(total / 256);             // 1024 blocks

    ApplyCoeffs_23261542875222_kernel<<<grid, block, 0, stream>>>(
        (const float4*)coeff, (const float4*)inp, (float4*)out, P4);
}